// Round 8
// baseline (240.504 us; speedup 1.0000x reference)
//
#include <hip/hip_runtime.h>
#include <hip/hip_bf16.h>

typedef __attribute__((ext_vector_type(8))) short bf16x8;
typedef __attribute__((ext_vector_type(4))) float f32x4;

#if defined(__has_builtin)
#if __has_builtin(__builtin_amdgcn_global_load_lds)
#define USE_GLOAD_LDS 1
#endif
#endif

__device__ __forceinline__ void gload_lds16(const void* g, void* ldsbase) {
#ifdef USE_GLOAD_LDS
    __builtin_amdgcn_global_load_lds(
        (__attribute__((address_space(1))) void*)(g),
        (__attribute__((address_space(3))) void*)(ldsbase), 16, 0, 0);
#endif
}

// ============ K1 early: pool (16384) + g_w transpose (512) + w_w cvt (256) + prepbias (32)
__global__ __launch_bounds__(256) void early_kernel(
        const float* __restrict__ x, float* __restrict__ xbar,
        const float* __restrict__ gw, const float* __restrict__ ww,
        __hip_bfloat16* __restrict__ gwt, __hip_bfloat16* __restrict__ wwb,
        const float* __restrict__ gb, const float* __restrict__ wb,
        const float* __restrict__ gamma, const float* __restrict__ beta,
        const float* __restrict__ mean, const float* __restrict__ var,
        float* __restrict__ inv, float* __restrict__ shift) {
    __shared__ float tile[32][33];
    int bid = blockIdx.x;
    int tid = threadIdx.x;
    if (bid < 16384) {
        int row = bid * 16 + (tid >> 4);
        int j = tid & 15;
        const float4* p = (const float4*)(x + (size_t)row * 128);
        float4 a = p[j * 2], b2 = p[j * 2 + 1];
        float s = a.x + a.y + a.z + a.w + b2.x + b2.y + b2.z + b2.w;
        s += __shfl_xor(s, 1); s += __shfl_xor(s, 2);
        s += __shfl_xor(s, 4); s += __shfl_xor(s, 8);
        if (j == 0) xbar[row] = s * (1.0f / 128.0f);
    } else if (bid < 16896) {
        int b2 = bid - 16384;
        int icb = b2 >> 5, cb = b2 & 31;
        int r = tid >> 5, c = tid & 31;
        #pragma unroll
        for (int i = 0; i < 4; i++)
            tile[r + i * 8][c] = gw[(size_t)(icb * 32 + r + i * 8) * 1024 + cb * 32 + c];
        __syncthreads();
        #pragma unroll
        for (int i = 0; i < 4; i++) {
            int cin = cb * 32 + r + i * 8;
            gwt[(size_t)cin * 512 + icb * 32 + c] = __float2bfloat16(tile[c][r + i * 8]);
        }
    } else if (bid < 17152) {
        int b2 = bid - 16896;
        size_t base = (size_t)b2 * 2048 + (size_t)tid * 8;
        const float4* src = (const float4*)(ww + base);
        float4 v0 = src[0], v1 = src[1];
        __hip_bfloat16 tmp[8];
        tmp[0] = __float2bfloat16(v0.x); tmp[1] = __float2bfloat16(v0.y);
        tmp[2] = __float2bfloat16(v0.z); tmp[3] = __float2bfloat16(v0.w);
        tmp[4] = __float2bfloat16(v1.x); tmp[5] = __float2bfloat16(v1.y);
        tmp[6] = __float2bfloat16(v1.z); tmp[7] = __float2bfloat16(v1.w);
        *(bf16x8*)(wwb + base) = *(const bf16x8*)tmp;
    } else {
        int b2 = bid - 17152;
        int wv = tid >> 6, l = tid & 63;
        int c = b2 * 32 + wv * 8 + (l >> 3);
        int j = l & 7;
        const float* wr = ww + (size_t)c * 512;
        float acc = 0.0f;
        #pragma unroll 8
        for (int k = j; k < 512; k += 8) acc += wr[k] * gb[k];
        acc += __shfl_xor(acc, 1); acc += __shfl_xor(acc, 2); acc += __shfl_xor(acc, 4);
        if (j == 0) {
            float cb2 = wb[c] + acc;
            float iv = gamma[c] * rsqrtf(var[c] + 1e-5f);
            inv[c] = iv;
            shift[c] = cb2 * iv + beta[c] - mean[c] * iv;
        }
    }
}

// ============ K2 stage2: thetaphi (1024) + prepM via MFMA (64)
__global__ __launch_bounds__(256) void stage2_kernel(
        const float* __restrict__ xbar,
        const float* __restrict__ tw, const float* __restrict__ tb,
        const float* __restrict__ pw, const float* __restrict__ pb,
        float* __restrict__ theta, float* __restrict__ phi,
        const __hip_bfloat16* __restrict__ wwb,
        const __hip_bfloat16* __restrict__ gwt,
        __hip_bfloat16* __restrict__ M) {
    __shared__ __align__(16) char smem[32768];
    int bid = blockIdx.x;
    int tid = threadIdx.x;
    if (bid < 1024) {
        float* xs = (float*)smem;
        int which = bid & 1;
        int icc = (bid >> 1) & 15;
        int b = bid >> 5;
        const float* w = which ? pw : tw;
        const float* bias = which ? pb : tb;
        float* out = which ? phi : theta;
        for (int i = tid; i < 8192; i += 256) xs[i] = xbar[b * 8192 + i];
        __syncthreads();
        int icl = tid >> 3;
        int t = tid & 7;
        int ic = icc * 32 + icl;
        const float* wr = w + (size_t)ic * 1024;
        float acc = 0.0f;
        #pragma unroll 8
        for (int k = 0; k < 1024; k++) acc += wr[k] * xs[k * 8 + t];
        out[((size_t)b * 512 + ic) * 8 + t] = acc + bias[ic];
    } else {
        __hip_bfloat16* As = (__hip_bfloat16*)smem;
        __hip_bfloat16* Bs = (__hip_bfloat16*)(smem + 8192);
        int b2 = bid - 1024;
        int mb = b2 >> 3, nb = b2 & 7;
        int c0 = mb * 128, n0 = nb * 128;
        int w = tid >> 6, l = tid & 63;
        int wr = w >> 1, wc = w & 1;
        const __hip_bfloat16* Ab = wwb + (size_t)c0 * 512;
        const __hip_bfloat16* Bb = gwt + (size_t)n0 * 512;
        int arow = tid >> 2, akq = tid & 3;
        f32x4 acc[4][4] = {};
        for (int kk = 0; kk < 16; ++kk) {
            int k0 = kk * 32;
#ifdef USE_GLOAD_LDS
            gload_lds16(Ab + (size_t)arow * 512 + k0 + akq * 8,        (char*)As + w * 1024);
            gload_lds16(Ab + (size_t)(arow + 64) * 512 + k0 + akq * 8, (char*)As + 4096 + w * 1024);
            gload_lds16(Bb + (size_t)arow * 512 + k0 + akq * 8,        (char*)Bs + w * 1024);
            gload_lds16(Bb + (size_t)(arow + 64) * 512 + k0 + akq * 8, (char*)Bs + 4096 + w * 1024);
#else
            *(bf16x8*)((char*)As + (size_t)tid * 16)        = *(const bf16x8*)(Ab + (size_t)arow * 512 + k0 + akq * 8);
            *(bf16x8*)((char*)As + 4096 + (size_t)tid * 16) = *(const bf16x8*)(Ab + (size_t)(arow + 64) * 512 + k0 + akq * 8);
            *(bf16x8*)((char*)Bs + (size_t)tid * 16)        = *(const bf16x8*)(Bb + (size_t)arow * 512 + k0 + akq * 8);
            *(bf16x8*)((char*)Bs + 4096 + (size_t)tid * 16) = *(const bf16x8*)(Bb + (size_t)(arow + 64) * 512 + k0 + akq * 8);
#endif
            __syncthreads();
            const __hip_bfloat16* Ap = As + ((size_t)(wr * 64 + (l & 15)) * 32) + (l >> 4) * 8;
            const __hip_bfloat16* Bp = Bs + ((size_t)(wc * 64 + (l & 15)) * 32) + (l >> 4) * 8;
            bf16x8 af[4], bfr[4];
            #pragma unroll
            for (int m = 0; m < 4; m++) af[m] = *(const bf16x8*)(Ap + m * 16 * 32);
            #pragma unroll
            for (int n = 0; n < 4; n++) bfr[n] = *(const bf16x8*)(Bp + n * 16 * 32);
            #pragma unroll
            for (int m = 0; m < 4; m++)
                #pragma unroll
                for (int n = 0; n < 4; n++)
                    acc[m][n] = __builtin_amdgcn_mfma_f32_16x16x32_bf16(af[m], bfr[n], acc[m][n], 0, 0, 0);
            __syncthreads();
        }
        int col = l & 15, rg = l >> 4;
        #pragma unroll
        for (int m = 0; m < 4; m++)
            #pragma unroll
            for (int j = 0; j < 4; j++) {
                int gc = c0 + wr * 64 + m * 16 + rg * 4 + j;
                #pragma unroll
                for (int n = 0; n < 4; n++)
                    M[(size_t)gc * 1024 + n0 + wc * 64 + n * 16 + col] = __float2bfloat16(acc[m][n][j]);
            }
    }
}

// ------------------------------------------------------- attn[b][t][s] = softmax_s(theta.phi)
__global__ __launch_bounds__(64) void attn_kernel(const float* __restrict__ theta,
                                                  const float* __restrict__ phi,
                                                  float* __restrict__ attn) {
    __shared__ float th[4096], ph[4096];
    int b = blockIdx.x, lane = threadIdx.x;
    for (int i = lane; i < 4096; i += 64) {
        th[i] = theta[(size_t)b * 4096 + i];
        ph[i] = phi[(size_t)b * 4096 + i];
    }
    __syncthreads();
    int t = lane >> 3, s = lane & 7;
    float f = 0.0f;
    #pragma unroll 8
    for (int ic = 0; ic < 512; ic++) f += th[ic * 8 + t] * ph[ic * 8 + s];
    float m = f;
    m = fmaxf(m, __shfl_xor(m, 1));
    m = fmaxf(m, __shfl_xor(m, 2));
    m = fmaxf(m, __shfl_xor(m, 4));
    float e = __expf(f - m);
    float sum = e;
    sum += __shfl_xor(sum, 1); sum += __shfl_xor(sum, 2); sum += __shfl_xor(sum, 4);
    attn[b * 64 + lane] = e / sum;
}

// ------------- mix + transpose: xm_t[b][t*128+hw][c] (bf16) = sum_s attn[b][t][s]*x[b][c][s][hw]
__global__ __launch_bounds__(256) void mix_kernel(const float* __restrict__ x,
                                                  const float* __restrict__ attn,
                                                  __hip_bfloat16* __restrict__ xmt) {
    int orig = blockIdx.x;
    int wg = (orig & 7) * 64 + (orig >> 3);
    int b = wg >> 4;
    int hwg = wg & 15;                          // group of 8 hw positions
    __shared__ float at[64];
    __shared__ float xs[8][8][33];              // [s][h][ci], ci-dim padded to 33
    int tid = threadIdx.x;
    if (tid < 64) at[tid] = attn[b * 64 + tid];
    int ci = tid >> 3, s = tid & 7;             // staging role: 32 c x 8 s
    int h = tid >> 5, cq = tid & 31;            // compute role: 8 h x 32 c
    const float* xb = x + ((size_t)b << 20);
    __hip_bfloat16* ob = xmt + ((size_t)b << 20);
    for (int cc = 0; cc < 32; ++cc) {
        const float4* src = (const float4*)(xb + ((size_t)(cc * 32 + ci) * 8 + s) * 128 + hwg * 8);
        float4 v0 = src[0], v1 = src[1];
        __syncthreads();
        xs[s][0][ci] = v0.x; xs[s][1][ci] = v0.y; xs[s][2][ci] = v0.z; xs[s][3][ci] = v0.w;
        xs[s][4][ci] = v1.x; xs[s][5][ci] = v1.y; xs[s][6][ci] = v1.z; xs[s][7][ci] = v1.w;
        __syncthreads();
        float xr[8];
        #pragma unroll
        for (int ss = 0; ss < 8; ss++) xr[ss] = xs[ss][h][cq];
        #pragma unroll
        for (int t = 0; t < 8; t++) {
            float o = 0.0f;
            #pragma unroll
            for (int ss = 0; ss < 8; ss++) o += at[t * 8 + ss] * xr[ss];
            ob[(size_t)(t * 128 + hwg * 8 + h) * 1024 + cc * 32 + cq] = __float2bfloat16(o);
        }
    }
}

// ===== 256x256 / BK=64 / 8-wave GEMM, m201-style 4-phase K-tile + counted vmcnt =====
// out[b][c][n] = inv[c] * sum_k M[c][k]*xmt[b][n][k] + shift[c] + x[b][c][n]
// 4 half-buffers (32 KiB each); half h staged 3 steps ahead. Per K64-tile, 4 phases
// of {ds_read subtile + ISSUE -> barrier -> lgkmcnt(0) -> 16 MFMA (setprio) -> barrier},
// vmcnt(8) twice per tile (counted; tail 8->4->0). Swizzle from R5 (proven, 0 conflicts).
__global__ __launch_bounds__(512, 2) void gemm256_kernel(
        const __hip_bfloat16* __restrict__ Mw,    // [1024][1024]  (c, k)
        const __hip_bfloat16* __restrict__ xmt,   // [32][1024][1024] (n, k)
        const float* __restrict__ x,              // [32][1024][1024] (c, n)
        const float* __restrict__ inv, const float* __restrict__ shift,
        float* __restrict__ out) {
    __shared__ __align__(16) __hip_bfloat16 HBs[65536];        // 128 KiB = 4 x 32 KiB
    char* AH = (char*)HBs;
    const int BUFB = 32768;

    int orig = blockIdx.x;
    int bid = (orig & 7) * 64 + (orig >> 3);      // XCD-chunked swizzle (512 % 8 == 0)
    int b = bid >> 4;
    int mb = (bid >> 2) & 3;
    int nb = bid & 3;
    int c0 = mb * 256, n0 = nb * 256;

    int tid = threadIdx.x;
    int w = tid >> 6, l = tid & 63;
    int wr = w >> 2, wc = w & 3;                  // wave out = 128(M) x 64(N)

    int sgl = (((l & 3) - ((l >> 3) & 3)) & 3);
    const __hip_bfloat16* aS = Mw + (size_t)(c0 + w * 16 + (l >> 2)) * 1024 + sgl * 8;
    const __hip_bfloat16* bS = xmt + ((size_t)b << 20) + (size_t)(n0 + w * 16 + (l >> 2)) * 1024 + sgl * 8;
    int stBase = w * 1024;

    int rdSlot = ((l >> 4) + (((l & 15) >> 1) & 3)) & 3;
    int aRdBase = (wr * 128 + (l & 15)) * 64 + rdSlot * 16;
    int bRdBase = 16384 + (wc * 64 + (l & 15)) * 64 + rdSlot * 16;

    f32x4 acc[8][4] = {};
    bf16x8 bfr[4];

    #define ISSUE(q3) do {                                                      \
        gload_lds16(aS,              AH + (q3) * BUFB + stBase);                \
        gload_lds16(aS + 128 * 1024, AH + (q3) * BUFB + stBase + 8192);         \
        gload_lds16(bS,              AH + (q3) * BUFB + 16384 + stBase);        \
        gload_lds16(bS + 128 * 1024, AH + (q3) * BUFB + 16384 + stBase + 8192); \
        aS += 32; bS += 32;                                                     \
    } while (0)

    #define V8 asm volatile("s_waitcnt vmcnt(8)" ::: "memory")
    #define V4 asm volatile("s_waitcnt vmcnt(4)" ::: "memory")
    #define V0 asm volatile("s_waitcnt vmcnt(0)" ::: "memory")
    #define VN ((void)0)
    #define SB0 __builtin_amdgcn_sched_barrier(0)
    #define BAR __builtin_amdgcn_s_barrier()
    #define LGKM0 asm volatile("s_waitcnt lgkmcnt(0)" ::: "memory")

    // phase LO: bfr + af[0..3] from half q, optional ISSUE, 16 MFMA (mh=0)
    #define PH_LO(q, DOISS, ibuf) do {                                          \
        const char* bp = AH + (q) * BUFB;                                       \
        _Pragma("unroll")                                                       \
        for (int n = 0; n < 4; ++n)                                             \
            bfr[n] = *(const bf16x8*)(bp + bRdBase + n * 1024);                 \
        bf16x8 af0, af1, af2, af3;                                              \
        af0 = *(const bf16x8*)(bp + aRdBase);                                   \
        af1 = *(const bf16x8*)(bp + aRdBase + 1024);                            \
        af2 = *(const bf16x8*)(bp + aRdBase + 2048);                            \
        af3 = *(const bf16x8*)(bp + aRdBase + 3072);                            \
        if (DOISS) ISSUE(ibuf);                                                 \
        SB0; BAR; LGKM0; SB0;                                                   \
        __builtin_amdgcn_s_setprio(1);                                          \
        _Pragma("unroll")                                                       \
        for (int n = 0; n < 4; ++n) {                                           \
            acc[0][n] = __builtin_amdgcn_mfma_f32_16x16x32_bf16(af0, bfr[n], acc[0][n], 0, 0, 0); \
            acc[1][n] = __builtin_amdgcn_mfma_f32_16x16x32_bf16(af1, bfr[n], acc[1][n], 0, 0, 0); \
            acc[2][n] = __builtin_amdgcn_mfma_f32_16x16x32_bf16(af2, bfr[n], acc[2][n], 0, 0, 0); \
            acc[3][n] = __builtin_amdgcn_mfma_f32_16x16x32_bf16(af3, bfr[n], acc[3][n], 0, 0, 0); \
        }                                                                       \
        __builtin_amdgcn_s_setprio(0);                                          \
        SB0; BAR;                                                               \
    } while (0)

    // phase HI: af[4..7] from half q, 16 MFMA (mh=1), tail wait, optional end barrier
    #define PH_HI(q, WAITM, LAST) do {                                          \
        const char* bp = AH + (q) * BUFB;                                       \
        bf16x8 af4, af5, af6, af7;                                              \
        af4 = *(const bf16x8*)(bp + aRdBase + 4096);                            \
        af5 = *(const bf16x8*)(bp + aRdBase + 5120);                            \
        af6 = *(const bf16x8*)(bp + aRdBase + 6144);                            \
        af7 = *(const bf16x8*)(bp + aRdBase + 7168);                            \
        SB0; BAR; LGKM0; SB0;                                                   \
        __builtin_amdgcn_s_setprio(1);                                          \
        _Pragma("unroll")                                                       \
        for (int n = 0; n < 4; ++n) {                                           \
            acc[4][n] = __builtin_amdgcn_mfma_f32_16x16x32_bf16(af4, bfr[n], acc[4][n], 0, 0, 0); \
            acc[5][n] = __builtin_amdgcn_mfma_f32_16x16x32_bf16(af5, bfr[n], acc[5][n], 0, 0, 0); \
            acc[6][n] = __builtin_amdgcn_mfma_f32_16x16x32_bf16(af6, bfr[n], acc[6][n], 0, 0, 0); \
            acc[7][n] = __builtin_amdgcn_mfma_f32_16x16x32_bf16(af7, bfr[n], acc[7][n], 0, 0, 0); \
        }                                                                       \
        __builtin_amdgcn_s_setprio(0);                                          \
        SB0; WAITM;                                                             \
        if (!(LAST)) { BAR; }                                                   \
    } while (0)

    // prologue: stage halves 0,1,2 (12 loads/thread); wait half 0 landed
    ISSUE(0); ISSUE(1); ISSUE(2);
    V8;
    BAR; SB0;

    // tiles 0..13 (7 pairs; static buffer parity)
    #pragma unroll 1
    for (int t2 = 0; t2 < 7; ++t2) {
        PH_LO(0, 1, 3); PH_HI(0, V8, 0); PH_LO(1, 1, 0); PH_HI(1, V8, 0);
        PH_LO(2, 1, 1); PH_HI(2, V8, 0); PH_LO(3, 1, 2); PH_HI(3, V8, 0);
    }
    // tile 14: reads halves 28,29; issues half 31 only
    PH_LO(0, 1, 3); PH_HI(0, V8, 0); PH_LO(1, 0, 0); PH_HI(1, V4, 0);
    // tile 15: reads halves 30,31; no issues
    PH_LO(2, 0, 0); PH_HI(2, V0, 0); PH_LO(3, 0, 0); PH_HI(3, VN, 1);

    #undef ISSUE
    #undef PH_LO
    #undef PH_HI
    #undef V8
    #undef V4
    #undef V0
    #undef VN
    #undef SB0
    #undef BAR
    #undef LGKM0

    // epilogue: C/D layout col = l&15, row = (l>>4)*4 + j
    int col = l & 15, rg = l >> 4;
    const float* xb = x + ((size_t)b << 20);
    float* ob = out + ((size_t)b << 20);
    #pragma unroll
    for (int mi = 0; mi < 8; ++mi) {
        #pragma unroll
        for (int j = 0; j < 4; ++j) {
            int gc = c0 + wr * 128 + mi * 16 + rg * 4 + j;
            float iv = inv[gc], sh = shift[gc];
            size_t rowoff = (size_t)gc * 1024 + n0 + wc * 64 + col;
            #pragma unroll
            for (int n = 0; n < 4; ++n) {
                size_t idx = rowoff + n * 16;
                ob[idx] = acc[mi][n][j] * iv + sh + xb[idx];
            }
        }
    }
}

extern "C" void kernel_launch(void* const* d_in, const int* in_sizes, int n_in,
                              void* d_out, int out_size, void* d_ws, size_t ws_size,
                              hipStream_t stream) {
    const float* x    = (const float*)d_in[0];
    const float* g_w  = (const float*)d_in[1];
    const float* g_b  = (const float*)d_in[2];
    const float* th_w = (const float*)d_in[3];
    const float* th_b = (const float*)d_in[4];
    const float* ph_w = (const float*)d_in[5];
    const float* ph_b = (const float*)d_in[6];
    const float* w_w  = (const float*)d_in[7];
    const float* w_b  = (const float*)d_in[8];
    const float* gam  = (const float*)d_in[9];
    const float* bet  = (const float*)d_in[10];
    const float* mea  = (const float*)d_in[11];
    const float* var  = (const float*)d_in[12];
    float* out = (float*)d_out;
    char* ws = (char*)d_ws;

    __hip_bfloat16* xmt = (__hip_bfloat16*)ws;                    // 64 MiB (written by mix, late)
    __hip_bfloat16* Mw  = (__hip_bfloat16*)(ws + 67108864);       // 2 MiB
    float* xbar  = (float*)(ws + 69206016);                       // 1 MiB
    float* theta = (float*)(ws + 70254592);                       // 512 KiB
    float* phi   = (float*)(ws + 70778880);                       // 512 KiB
    float* attn  = (float*)(ws + 71303168);                       // 8 KiB
    float* inv   = (float*)(ws + 71311360);                       // 4 KiB
    float* shift = (float*)(ws + 71315456);                       // 4 KiB
    // gwt/wwb overlay the xmt region: consumed by stage2 (prepM) BEFORE mix writes xmt
    __hip_bfloat16* gwt = (__hip_bfloat16*)ws;                    // 1 MiB
    __hip_bfloat16* wwb = (__hip_bfloat16*)(ws + 1048576);        // 1 MiB

    hipLaunchKernelGGL(early_kernel, dim3(17184), dim3(256), 0, stream,
                       x, xbar, g_w, w_w, gwt, wwb,
                       g_b, w_b, gam, bet, mea, var, inv, shift);
    hipLaunchKernelGGL(stage2_kernel, dim3(1088), dim3(256), 0, stream,
                       xbar, th_w, th_b, ph_w, ph_b, theta, phi, wwb, gwt, Mw);
    hipLaunchKernelGGL(attn_kernel, dim3(32), dim3(64), 0, stream, theta, phi, attn);
    hipLaunchKernelGGL(mix_kernel, dim3(512), dim3(256), 0, stream, x, attn, xmt);
    hipLaunchKernelGGL(gemm256_kernel, dim3(512), dim3(512), 0, stream,
                       Mw, xmt, x, inv, shift, out);
}

// Round 9
// 233.460 us; speedup vs baseline: 1.0302x; 1.0302x over previous
//
#include <hip/hip_runtime.h>
#include <hip/hip_bf16.h>

typedef __attribute__((ext_vector_type(8))) short bf16x8;
typedef __attribute__((ext_vector_type(4))) float f32x4;

#if defined(__has_builtin)
#if __has_builtin(__builtin_amdgcn_global_load_lds)
#define USE_GLOAD_LDS 1
#endif
#endif

__device__ __forceinline__ void gload_lds16(const void* g, void* ldsbase) {
#ifdef USE_GLOAD_LDS
    __builtin_amdgcn_global_load_lds(
        (__attribute__((address_space(1))) void*)(g),
        (__attribute__((address_space(3))) void*)(ldsbase), 16, 0, 0);
#endif
}

// ============ K1 early: pool (16384) + g_w transpose (512) + w_w cvt (256) + prepbias (32)
__global__ __launch_bounds__(256) void early_kernel(
        const float* __restrict__ x, float* __restrict__ xbar,
        const float* __restrict__ gw, const float* __restrict__ ww,
        __hip_bfloat16* __restrict__ gwt, __hip_bfloat16* __restrict__ wwb,
        const float* __restrict__ gb, const float* __restrict__ wb,
        const float* __restrict__ gamma, const float* __restrict__ beta,
        const float* __restrict__ mean, const float* __restrict__ var,
        float* __restrict__ inv, float* __restrict__ shift) {
    __shared__ float tile[32][33];
    int bid = blockIdx.x;
    int tid = threadIdx.x;
    if (bid < 16384) {
        int row = bid * 16 + (tid >> 4);
        int j = tid & 15;
        const float4* p = (const float4*)(x + (size_t)row * 128);
        float4 a = p[j * 2], b2 = p[j * 2 + 1];
        float s = a.x + a.y + a.z + a.w + b2.x + b2.y + b2.z + b2.w;
        s += __shfl_xor(s, 1); s += __shfl_xor(s, 2);
        s += __shfl_xor(s, 4); s += __shfl_xor(s, 8);
        if (j == 0) xbar[row] = s * (1.0f / 128.0f);
    } else if (bid < 16896) {
        int b2 = bid - 16384;
        int icb = b2 >> 5, cb = b2 & 31;
        int r = tid >> 5, c = tid & 31;
        #pragma unroll
        for (int i = 0; i < 4; i++)
            tile[r + i * 8][c] = gw[(size_t)(icb * 32 + r + i * 8) * 1024 + cb * 32 + c];
        __syncthreads();
        #pragma unroll
        for (int i = 0; i < 4; i++) {
            int cin = cb * 32 + r + i * 8;
            gwt[(size_t)cin * 512 + icb * 32 + c] = __float2bfloat16(tile[c][r + i * 8]);
        }
    } else if (bid < 17152) {
        int b2 = bid - 16896;
        size_t base = (size_t)b2 * 2048 + (size_t)tid * 8;
        const float4* src = (const float4*)(ww + base);
        float4 v0 = src[0], v1 = src[1];
        __hip_bfloat16 tmp[8];
        tmp[0] = __float2bfloat16(v0.x); tmp[1] = __float2bfloat16(v0.y);
        tmp[2] = __float2bfloat16(v0.z); tmp[3] = __float2bfloat16(v0.w);
        tmp[4] = __float2bfloat16(v1.x); tmp[5] = __float2bfloat16(v1.y);
        tmp[6] = __float2bfloat16(v1.z); tmp[7] = __float2bfloat16(v1.w);
        *(bf16x8*)(wwb + base) = *(const bf16x8*)tmp;
    } else {
        int b2 = bid - 17152;
        int wv = tid >> 6, l = tid & 63;
        int c = b2 * 32 + wv * 8 + (l >> 3);
        int j = l & 7;
        const float* wr = ww + (size_t)c * 512;
        float acc = 0.0f;
        #pragma unroll 8
        for (int k = j; k < 512; k += 8) acc += wr[k] * gb[k];
        acc += __shfl_xor(acc, 1); acc += __shfl_xor(acc, 2); acc += __shfl_xor(acc, 4);
        if (j == 0) {
            float cb2 = wb[c] + acc;
            float iv = gamma[c] * rsqrtf(var[c] + 1e-5f);
            inv[c] = iv;
            shift[c] = cb2 * iv + beta[c] - mean[c] * iv;
        }
    }
}

// ============ K2 stage2: thetaphi (1024) + prepM via MFMA (64)
__global__ __launch_bounds__(256) void stage2_kernel(
        const float* __restrict__ xbar,
        const float* __restrict__ tw, const float* __restrict__ tb,
        const float* __restrict__ pw, const float* __restrict__ pb,
        float* __restrict__ theta, float* __restrict__ phi,
        const __hip_bfloat16* __restrict__ wwb,
        const __hip_bfloat16* __restrict__ gwt,
        __hip_bfloat16* __restrict__ M) {
    __shared__ __align__(16) char smem[32768];
    int bid = blockIdx.x;
    int tid = threadIdx.x;
    if (bid < 1024) {
        float* xs = (float*)smem;
        int which = bid & 1;
        int icc = (bid >> 1) & 15;
        int b = bid >> 5;
        const float* w = which ? pw : tw;
        const float* bias = which ? pb : tb;
        float* out = which ? phi : theta;
        for (int i = tid; i < 8192; i += 256) xs[i] = xbar[b * 8192 + i];
        __syncthreads();
        int icl = tid >> 3;
        int t = tid & 7;
        int ic = icc * 32 + icl;
        const float* wr = w + (size_t)ic * 1024;
        float acc = 0.0f;
        #pragma unroll 8
        for (int k = 0; k < 1024; k++) acc += wr[k] * xs[k * 8 + t];
        out[((size_t)b * 512 + ic) * 8 + t] = acc + bias[ic];
    } else {
        __hip_bfloat16* As = (__hip_bfloat16*)smem;
        __hip_bfloat16* Bs = (__hip_bfloat16*)(smem + 8192);
        int b2 = bid - 1024;
        int mb = b2 >> 3, nb = b2 & 7;
        int c0 = mb * 128, n0 = nb * 128;
        int w = tid >> 6, l = tid & 63;
        int wr = w >> 1, wc = w & 1;
        const __hip_bfloat16* Ab = wwb + (size_t)c0 * 512;
        const __hip_bfloat16* Bb = gwt + (size_t)n0 * 512;
        int arow = tid >> 2, akq = tid & 3;
        f32x4 acc[4][4] = {};
        for (int kk = 0; kk < 16; ++kk) {
            int k0 = kk * 32;
#ifdef USE_GLOAD_LDS
            gload_lds16(Ab + (size_t)arow * 512 + k0 + akq * 8,        (char*)As + w * 1024);
            gload_lds16(Ab + (size_t)(arow + 64) * 512 + k0 + akq * 8, (char*)As + 4096 + w * 1024);
            gload_lds16(Bb + (size_t)arow * 512 + k0 + akq * 8,        (char*)Bs + w * 1024);
            gload_lds16(Bb + (size_t)(arow + 64) * 512 + k0 + akq * 8, (char*)Bs + 4096 + w * 1024);
#else
            *(bf16x8*)((char*)As + (size_t)tid * 16)        = *(const bf16x8*)(Ab + (size_t)arow * 512 + k0 + akq * 8);
            *(bf16x8*)((char*)As + 4096 + (size_t)tid * 16) = *(const bf16x8*)(Ab + (size_t)(arow + 64) * 512 + k0 + akq * 8);
            *(bf16x8*)((char*)Bs + (size_t)tid * 16)        = *(const bf16x8*)(Bb + (size_t)arow * 512 + k0 + akq * 8);
            *(bf16x8*)((char*)Bs + 4096 + (size_t)tid * 16) = *(const bf16x8*)(Bb + (size_t)(arow + 64) * 512 + k0 + akq * 8);
#endif
            __syncthreads();
            const __hip_bfloat16* Ap = As + ((size_t)(wr * 64 + (l & 15)) * 32) + (l >> 4) * 8;
            const __hip_bfloat16* Bp = Bs + ((size_t)(wc * 64 + (l & 15)) * 32) + (l >> 4) * 8;
            bf16x8 af[4], bfr[4];
            #pragma unroll
            for (int m = 0; m < 4; m++) af[m] = *(const bf16x8*)(Ap + m * 16 * 32);
            #pragma unroll
            for (int n = 0; n < 4; n++) bfr[n] = *(const bf16x8*)(Bp + n * 16 * 32);
            #pragma unroll
            for (int m = 0; m < 4; m++)
                #pragma unroll
                for (int n = 0; n < 4; n++)
                    acc[m][n] = __builtin_amdgcn_mfma_f32_16x16x32_bf16(af[m], bfr[n], acc[m][n], 0, 0, 0);
            __syncthreads();
        }
        int col = l & 15, rg = l >> 4;
        #pragma unroll
        for (int m = 0; m < 4; m++)
            #pragma unroll
            for (int j = 0; j < 4; j++) {
                int gc = c0 + wr * 64 + m * 16 + rg * 4 + j;
                #pragma unroll
                for (int n = 0; n < 4; n++)
                    M[(size_t)gc * 1024 + n0 + wc * 64 + n * 16 + col] = __float2bfloat16(acc[m][n][j]);
            }
    }
}

// ------------------------------------------------------- attn[b][t][s] = softmax_s(theta.phi)
__global__ __launch_bounds__(64) void attn_kernel(const float* __restrict__ theta,
                                                  const float* __restrict__ phi,
                                                  float* __restrict__ attn) {
    __shared__ float th[4096], ph[4096];
    int b = blockIdx.x, lane = threadIdx.x;
    for (int i = lane; i < 4096; i += 64) {
        th[i] = theta[(size_t)b * 4096 + i];
        ph[i] = phi[(size_t)b * 4096 + i];
    }
    __syncthreads();
    int t = lane >> 3, s = lane & 7;
    float f = 0.0f;
    #pragma unroll 8
    for (int ic = 0; ic < 512; ic++) f += th[ic * 8 + t] * ph[ic * 8 + s];
    float m = f;
    m = fmaxf(m, __shfl_xor(m, 1));
    m = fmaxf(m, __shfl_xor(m, 2));
    m = fmaxf(m, __shfl_xor(m, 4));
    float e = __expf(f - m);
    float sum = e;
    sum += __shfl_xor(sum, 1); sum += __shfl_xor(sum, 2); sum += __shfl_xor(sum, 4);
    attn[b * 64 + lane] = e / sum;
}

// ------------- mix + transpose: xm_t[b][t*128+hw][c] (bf16) = sum_s attn[b][t][s]*x[b][c][s][hw]
__global__ __launch_bounds__(256) void mix_kernel(const float* __restrict__ x,
                                                  const float* __restrict__ attn,
                                                  __hip_bfloat16* __restrict__ xmt) {
    int orig = blockIdx.x;
    int wg = (orig & 7) * 64 + (orig >> 3);
    int b = wg >> 4;
    int hwg = wg & 15;                          // group of 8 hw positions
    __shared__ float at[64];
    __shared__ float xs[8][8][33];              // [s][h][ci], ci-dim padded to 33
    int tid = threadIdx.x;
    if (tid < 64) at[tid] = attn[b * 64 + tid];
    int ci = tid >> 3, s = tid & 7;             // staging role: 32 c x 8 s
    int h = tid >> 5, cq = tid & 31;            // compute role: 8 h x 32 c
    const float* xb = x + ((size_t)b << 20);
    __hip_bfloat16* ob = xmt + ((size_t)b << 20);
    for (int cc = 0; cc < 32; ++cc) {
        const float4* src = (const float4*)(xb + ((size_t)(cc * 32 + ci) * 8 + s) * 128 + hwg * 8);
        float4 v0 = src[0], v1 = src[1];
        __syncthreads();
        xs[s][0][ci] = v0.x; xs[s][1][ci] = v0.y; xs[s][2][ci] = v0.z; xs[s][3][ci] = v0.w;
        xs[s][4][ci] = v1.x; xs[s][5][ci] = v1.y; xs[s][6][ci] = v1.z; xs[s][7][ci] = v1.w;
        __syncthreads();
        float xr[8];
        #pragma unroll
        for (int ss = 0; ss < 8; ss++) xr[ss] = xs[ss][h][cq];
        #pragma unroll
        for (int t = 0; t < 8; t++) {
            float o = 0.0f;
            #pragma unroll
            for (int ss = 0; ss < 8; ss++) o += at[t * 8 + ss] * xr[ss];
            ob[(size_t)(t * 128 + hwg * 8 + h) * 1024 + cc * 32 + cq] = __float2bfloat16(o);
        }
    }
}

// ===== 128x128-tile / 4-wave GEMM, K32 double-buffer + counted vmcnt, 3 blocks/CU =====
// out[b][c][n] = inv[c] * sum_k M[c][k]*xmt[b][n][k] + shift[c] + x[b][c][n]
// LDS: 2 half-buffers x (A 128x32 + B 128x32) bf16 = 32 KiB -> 3 blocks/CU (12 waves).
// Step h (buf q=h&1): {8 ds_read(q) -> lgkmcnt(0) -> BAR -> ISSUE(q <- data h+2)
//  -> 16 MFMA (setprio) -> vmcnt(4) [data h+1 landed] -> BAR}.
// Swizzle (R5-proven): LDS slot l&3 at row r holds global slot ((l&3)-((r>>1)&3))&3;
// read rdSlot = ((l>>4)+(((l&15)>>1)&3))&3 -> lane gets k-chunk (l>>4)*8. 0 conflicts.
__global__ __launch_bounds__(256, 3) void gemm128_kernel(
        const __hip_bfloat16* __restrict__ Mw,    // [1024][1024]  (c, k)
        const __hip_bfloat16* __restrict__ xmt,   // [32][1024][1024] (n, k)
        const float* __restrict__ x,              // [32][1024][1024] (c, n)
        const float* __restrict__ inv, const float* __restrict__ shift,
        float* __restrict__ out) {
    __shared__ __align__(16) __hip_bfloat16 HBs[16384];        // 32 KiB = 2 x 16 KiB
    char* AH = (char*)HBs;
    const int BUFB = 16384;

    int orig = blockIdx.x;
    int bid = (orig & 7) * 256 + (orig >> 3);     // XCD chunk: 4 batches/XCD -> L2 locality
    int b = bid >> 6;
    int mb = (bid >> 3) & 7;
    int nb = bid & 7;
    int c0 = mb * 128, n0 = nb * 128;

    int tid = threadIdx.x;
    int w = tid >> 6, l = tid & 63;
    int wr = w >> 1, wc = w & 1;                  // 2x2 waves; wave out = 64(M) x 64(N)

    // staging: wave-call covers rows w*16+(l>>2) (+64 for 2nd call), LDS slot l&3
    int sgl = (((l & 3) - ((l >> 3) & 3)) & 3);
    const __hip_bfloat16* aS = Mw + (size_t)(c0 + w * 16 + (l >> 2)) * 1024 + sgl * 8;
    const __hip_bfloat16* bS = xmt + ((size_t)b << 20) + (size_t)(n0 + w * 16 + (l >> 2)) * 1024 + sgl * 8;
    int stBase = w * 1024;

    int rdSlot = ((l >> 4) + (((l & 15) >> 1) & 3)) & 3;
    int aRdBase = (wr * 64 + (l & 15)) * 64 + rdSlot * 16;          // fragment mi: +mi*1024
    int bRdBase = 8192 + (wc * 64 + (l & 15)) * 64 + rdSlot * 16;   // fragment n: +n*1024

    f32x4 acc[4][4] = {};

    #define ISSUE(q) do {                                                       \
        gload_lds16(aS,             AH + (q) * BUFB + stBase);                  \
        gload_lds16(aS + 64 * 1024, AH + (q) * BUFB + 4096 + stBase);           \
        gload_lds16(bS,             AH + (q) * BUFB + 8192 + stBase);           \
        gload_lds16(bS + 64 * 1024, AH + (q) * BUFB + 12288 + stBase);          \
        aS += 32; bS += 32;                                                     \
    } while (0)

    #define V4 asm volatile("s_waitcnt vmcnt(4)" ::: "memory")
    #define V0 asm volatile("s_waitcnt vmcnt(0)" ::: "memory")
    #define SB0 __builtin_amdgcn_sched_barrier(0)
    #define BAR __builtin_amdgcn_s_barrier()
    #define LGKM0 asm volatile("s_waitcnt lgkmcnt(0)" ::: "memory")

    // MODE: 0 = issue + vmcnt(4), 1 = no issue + vmcnt(0), 2 = last (no sync)
    #define HSTEP(q, MODE) do {                                                 \
        const char* bp = AH + (q) * BUFB;                                       \
        bf16x8 af0 = *(const bf16x8*)(bp + aRdBase);                            \
        bf16x8 af1 = *(const bf16x8*)(bp + aRdBase + 1024);                     \
        bf16x8 af2 = *(const bf16x8*)(bp + aRdBase + 2048);                     \
        bf16x8 af3 = *(const bf16x8*)(bp + aRdBase + 3072);                     \
        bf16x8 bf0 = *(const bf16x8*)(bp + bRdBase);                            \
        bf16x8 bf1 = *(const bf16x8*)(bp + bRdBase + 1024);                     \
        bf16x8 bf2 = *(const bf16x8*)(bp + bRdBase + 2048);                     \
        bf16x8 bf3 = *(const bf16x8*)(bp + bRdBase + 3072);                     \
        LGKM0; SB0;                                                             \
        BAR;                          /* all waves done reading buf q */        \
        if ((MODE) == 0) ISSUE(q);    /* refill q with data for h+2 */          \
        SB0;                                                                    \
        __builtin_amdgcn_s_setprio(1);                                          \
        _Pragma("unroll")                                                       \
        for (int n = 0; n < 4; ++n) {                                           \
            bf16x8 bfn = (n == 0) ? bf0 : (n == 1) ? bf1 : (n == 2) ? bf2 : bf3;\
            acc[0][n] = __builtin_amdgcn_mfma_f32_16x16x32_bf16(af0, bfn, acc[0][n], 0, 0, 0); \
            acc[1][n] = __builtin_amdgcn_mfma_f32_16x16x32_bf16(af1, bfn, acc[1][n], 0, 0, 0); \
            acc[2][n] = __builtin_amdgcn_mfma_f32_16x16x32_bf16(af2, bfn, acc[2][n], 0, 0, 0); \
            acc[3][n] = __builtin_amdgcn_mfma_f32_16x16x32_bf16(af3, bfn, acc[3][n], 0, 0, 0); \
        }                                                                       \
        __builtin_amdgcn_s_setprio(0);                                          \
        SB0;                                                                    \
        if ((MODE) == 0) { V4; BAR; SB0; }                                      \
        else if ((MODE) == 1) { V0; BAR; SB0; }                                 \
    } while (0)

    // prologue: stage halves 0,1 (8 loads/thread); wait half 0 (4 = half 1 in flight)
    ISSUE(0); ISSUE(1);
    V4; BAR; SB0;

    // 32 half-steps of K=32; steps 0..29 refill, 30 drains, 31 bare
    #pragma unroll 1
    for (int t = 0; t < 15; ++t) {
        HSTEP(0, 0);
        HSTEP(1, 0);
    }
    HSTEP(0, 1);
    HSTEP(1, 2);

    #undef ISSUE
    #undef HSTEP
    #undef V4
    #undef V0
    #undef SB0
    #undef BAR
    #undef LGKM0

    // epilogue: C/D layout col = l&15, row = (l>>4)*4 + j
    int col = l & 15, rg = l >> 4;
    const float* xb = x + ((size_t)b << 20);
    float* ob = out + ((size_t)b << 20);
    #pragma unroll
    for (int mi = 0; mi < 4; ++mi) {
        #pragma unroll
        for (int j = 0; j < 4; ++j) {
            int gc = c0 + wr * 64 + mi * 16 + rg * 4 + j;
            float iv = inv[gc], sh = shift[gc];
            size_t rowoff = (size_t)gc * 1024 + n0 + wc * 64 + col;
            #pragma unroll
            for (int n = 0; n < 4; ++n) {
                size_t idx = rowoff + n * 16;
                ob[idx] = acc[mi][n][j] * iv + sh + xb[idx];
            }
        }
    }
}

extern "C" void kernel_launch(void* const* d_in, const int* in_sizes, int n_in,
                              void* d_out, int out_size, void* d_ws, size_t ws_size,
                              hipStream_t stream) {
    const float* x    = (const float*)d_in[0];
    const float* g_w  = (const float*)d_in[1];
    const float* g_b  = (const float*)d_in[2];
    const float* th_w = (const float*)d_in[3];
    const float* th_b = (const float*)d_in[4];
    const float* ph_w = (const float*)d_in[5];
    const float* ph_b = (const float*)d_in[6];
    const float* w_w  = (const float*)d_in[7];
    const float* w_b  = (const float*)d_in[8];
    const float* gam  = (const float*)d_in[9];
    const float* bet  = (const float*)d_in[10];
    const float* mea  = (const float*)d_in[11];
    const float* var  = (const float*)d_in[12];
    float* out = (float*)d_out;
    char* ws = (char*)d_ws;

    __hip_bfloat16* xmt = (__hip_bfloat16*)ws;                    // 64 MiB (written by mix, late)
    __hip_bfloat16* Mw  = (__hip_bfloat16*)(ws + 67108864);       // 2 MiB
    float* xbar  = (float*)(ws + 69206016);                       // 1 MiB
    float* theta = (float*)(ws + 70254592);                       // 512 KiB
    float* phi   = (float*)(ws + 70778880);                       // 512 KiB
    float* attn  = (float*)(ws + 71303168);                       // 8 KiB
    float* inv   = (float*)(ws + 71311360);                       // 4 KiB
    float* shift = (float*)(ws + 71315456);                       // 4 KiB
    // gwt/wwb overlay the xmt region: consumed by stage2 (prepM) BEFORE mix writes xmt
    __hip_bfloat16* gwt = (__hip_bfloat16*)ws;                    // 1 MiB
    __hip_bfloat16* wwb = (__hip_bfloat16*)(ws + 1048576);        // 1 MiB

    hipLaunchKernelGGL(early_kernel, dim3(17184), dim3(256), 0, stream,
                       x, xbar, g_w, w_w, gwt, wwb,
                       g_b, w_b, gam, bet, mea, var, inv, shift);
    hipLaunchKernelGGL(stage2_kernel, dim3(1088), dim3(256), 0, stream,
                       xbar, th_w, th_b, ph_w, ph_b, theta, phi, wwb, gwt, Mw);
    hipLaunchKernelGGL(attn_kernel, dim3(32), dim3(64), 0, stream, theta, phi, attn);
    hipLaunchKernelGGL(mix_kernel, dim3(512), dim3(256), 0, stream, x, attn, xmt);
    hipLaunchKernelGGL(gemm128_kernel, dim3(2048), dim3(256), 0, stream,
                       Mw, xmt, x, inv, shift, out);
}

// Round 10
// 219.584 us; speedup vs baseline: 1.0953x; 1.0632x over previous
//
#include <hip/hip_runtime.h>
#include <hip/hip_bf16.h>

typedef __attribute__((ext_vector_type(8))) short bf16x8;
typedef __attribute__((ext_vector_type(4))) float f32x4;

#if defined(__has_builtin)
#if __has_builtin(__builtin_amdgcn_global_load_lds)
#define USE_GLOAD_LDS 1
#endif
#endif

__device__ __forceinline__ void gload_lds16(const void* g, void* ldsbase) {
#ifdef USE_GLOAD_LDS
    __builtin_amdgcn_global_load_lds(
        (__attribute__((address_space(1))) void*)(g),
        (__attribute__((address_space(3))) void*)(ldsbase), 16, 0, 0);
#endif
}

__device__ __forceinline__ unsigned short f2bf(float f) {
    __hip_bfloat16 h = __float2bfloat16(f);
    return *reinterpret_cast<unsigned short*>(&h);
}

// ============ K1 early: pool (16384) + g_w transpose (512) + w_w cvt (256) + prepbias (32)
__global__ __launch_bounds__(256) void early_kernel(
        const float* __restrict__ x, float* __restrict__ xbar,
        const float* __restrict__ gw, const float* __restrict__ ww,
        __hip_bfloat16* __restrict__ gwt, __hip_bfloat16* __restrict__ wwb,
        const float* __restrict__ gb, const float* __restrict__ wb,
        const float* __restrict__ gamma, const float* __restrict__ beta,
        const float* __restrict__ mean, const float* __restrict__ var,
        float* __restrict__ inv, float* __restrict__ shift) {
    __shared__ float tile[32][33];
    int bid = blockIdx.x;
    int tid = threadIdx.x;
    if (bid < 16384) {
        int row = bid * 16 + (tid >> 4);
        int j = tid & 15;
        const float4* p = (const float4*)(x + (size_t)row * 128);
        float4 a = p[j * 2], b2 = p[j * 2 + 1];
        float s = a.x + a.y + a.z + a.w + b2.x + b2.y + b2.z + b2.w;
        s += __shfl_xor(s, 1); s += __shfl_xor(s, 2);
        s += __shfl_xor(s, 4); s += __shfl_xor(s, 8);
        if (j == 0) xbar[row] = s * (1.0f / 128.0f);
    } else if (bid < 16896) {
        int b2 = bid - 16384;
        int icb = b2 >> 5, cb = b2 & 31;
        int r = tid >> 5, c = tid & 31;
        #pragma unroll
        for (int i = 0; i < 4; i++)
            tile[r + i * 8][c] = gw[(size_t)(icb * 32 + r + i * 8) * 1024 + cb * 32 + c];
        __syncthreads();
        #pragma unroll
        for (int i = 0; i < 4; i++) {
            int cin = cb * 32 + r + i * 8;
            gwt[(size_t)cin * 512 + icb * 32 + c] = __float2bfloat16(tile[c][r + i * 8]);
        }
    } else if (bid < 17152) {
        int b2 = bid - 16896;
        size_t base = (size_t)b2 * 2048 + (size_t)tid * 8;
        const float4* src = (const float4*)(ww + base);
        float4 v0 = src[0], v1 = src[1];
        __hip_bfloat16 tmp[8];
        tmp[0] = __float2bfloat16(v0.x); tmp[1] = __float2bfloat16(v0.y);
        tmp[2] = __float2bfloat16(v0.z); tmp[3] = __float2bfloat16(v0.w);
        tmp[4] = __float2bfloat16(v1.x); tmp[5] = __float2bfloat16(v1.y);
        tmp[6] = __float2bfloat16(v1.z); tmp[7] = __float2bfloat16(v1.w);
        *(bf16x8*)(wwb + base) = *(const bf16x8*)tmp;
    } else {
        int b2 = bid - 17152;
        int wv = tid >> 6, l = tid & 63;
        int c = b2 * 32 + wv * 8 + (l >> 3);
        int j = l & 7;
        const float* wr = ww + (size_t)c * 512;
        float acc = 0.0f;
        #pragma unroll 8
        for (int k = j; k < 512; k += 8) acc += wr[k] * gb[k];
        acc += __shfl_xor(acc, 1); acc += __shfl_xor(acc, 2); acc += __shfl_xor(acc, 4);
        if (j == 0) {
            float cb2 = wb[c] + acc;
            float iv = gamma[c] * rsqrtf(var[c] + 1e-5f);
            inv[c] = iv;
            shift[c] = cb2 * iv + beta[c] - mean[c] * iv;
        }
    }
}

// ============ K2 stage2: thetaphi (1024, LDS-transposed b128 reads) + prepM via MFMA (64)
__global__ __launch_bounds__(256) void stage2_kernel(
        const float* __restrict__ xbar,
        const float* __restrict__ tw, const float* __restrict__ tb,
        const float* __restrict__ pw, const float* __restrict__ pb,
        float* __restrict__ theta, float* __restrict__ phi,
        const __hip_bfloat16* __restrict__ wwb,
        const __hip_bfloat16* __restrict__ gwt,
        __hip_bfloat16* __restrict__ M) {
    __shared__ __align__(16) char smem[33024];
    int bid = blockIdx.x;
    int tid = threadIdx.x;
    if (bid < 1024) {
        // theta/phi: [b][ic][t] = W @ xbar[b][:][t] + bias ; xs transposed [t][1028]
        float* xs = (float*)smem;
        int which = bid & 1;
        int icc = (bid >> 1) & 15;
        int b = bid >> 5;
        const float* w = which ? pw : tw;
        const float* bias = which ? pb : tb;
        float* out = which ? phi : theta;
        const float* xbb = xbar + b * 8192;
        #pragma unroll
        for (int k = 0; k < 8; ++k) {
            int f4 = tid + k * 256;          // 0..2047
            float4 v = *(const float4*)(xbb + (size_t)f4 * 4);
            int c = f4 >> 1;
            int t0 = (f4 & 1) * 4;
            xs[(t0 + 0) * 1028 + c] = v.x;
            xs[(t0 + 1) * 1028 + c] = v.y;
            xs[(t0 + 2) * 1028 + c] = v.z;
            xs[(t0 + 3) * 1028 + c] = v.w;
        }
        __syncthreads();
        int icl = tid >> 3, t = tid & 7;
        int ic = icc * 32 + icl;
        const float* wr = w + (size_t)ic * 1024;
        const float* xr = xs + t * 1028;
        float a0 = 0.0f, a1 = 0.0f;
        #pragma unroll 4
        for (int k = 0; k < 1024; k += 8) {
            float4 wv0 = *(const float4*)(wr + k);
            float4 wv1 = *(const float4*)(wr + k + 4);
            float4 xv0 = *(const float4*)(xr + k);
            float4 xv1 = *(const float4*)(xr + k + 4);
            a0 = fmaf(wv0.x, xv0.x, a0); a0 = fmaf(wv0.y, xv0.y, a0);
            a0 = fmaf(wv0.z, xv0.z, a0); a0 = fmaf(wv0.w, xv0.w, a0);
            a1 = fmaf(wv1.x, xv1.x, a1); a1 = fmaf(wv1.y, xv1.y, a1);
            a1 = fmaf(wv1.z, xv1.z, a1); a1 = fmaf(wv1.w, xv1.w, a1);
        }
        out[((size_t)b * 512 + ic) * 8 + t] = a0 + a1 + bias[ic];
    } else {
        __hip_bfloat16* As = (__hip_bfloat16*)smem;
        __hip_bfloat16* Bs = (__hip_bfloat16*)(smem + 8192);
        int b2 = bid - 1024;
        int mb = b2 >> 3, nb = b2 & 7;
        int c0 = mb * 128, n0 = nb * 128;
        int w = tid >> 6, l = tid & 63;
        int wr = w >> 1, wc = w & 1;
        const __hip_bfloat16* Ab = wwb + (size_t)c0 * 512;
        const __hip_bfloat16* Bb = gwt + (size_t)n0 * 512;
        int arow = tid >> 2, akq = tid & 3;
        f32x4 acc[4][4] = {};
        for (int kk = 0; kk < 16; ++kk) {
            int k0 = kk * 32;
#ifdef USE_GLOAD_LDS
            gload_lds16(Ab + (size_t)arow * 512 + k0 + akq * 8,        (char*)As + w * 1024);
            gload_lds16(Ab + (size_t)(arow + 64) * 512 + k0 + akq * 8, (char*)As + 4096 + w * 1024);
            gload_lds16(Bb + (size_t)arow * 512 + k0 + akq * 8,        (char*)Bs + w * 1024);
            gload_lds16(Bb + (size_t)(arow + 64) * 512 + k0 + akq * 8, (char*)Bs + 4096 + w * 1024);
#else
            *(bf16x8*)((char*)As + (size_t)tid * 16)        = *(const bf16x8*)(Ab + (size_t)arow * 512 + k0 + akq * 8);
            *(bf16x8*)((char*)As + 4096 + (size_t)tid * 16) = *(const bf16x8*)(Ab + (size_t)(arow + 64) * 512 + k0 + akq * 8);
            *(bf16x8*)((char*)Bs + (size_t)tid * 16)        = *(const bf16x8*)(Bb + (size_t)arow * 512 + k0 + akq * 8);
            *(bf16x8*)((char*)Bs + 4096 + (size_t)tid * 16) = *(const bf16x8*)(Bb + (size_t)(arow + 64) * 512 + k0 + akq * 8);
#endif
            __syncthreads();
            const __hip_bfloat16* Ap = As + ((size_t)(wr * 64 + (l & 15)) * 32) + (l >> 4) * 8;
            const __hip_bfloat16* Bp = Bs + ((size_t)(wc * 64 + (l & 15)) * 32) + (l >> 4) * 8;
            bf16x8 af[4], bfr[4];
            #pragma unroll
            for (int m = 0; m < 4; m++) af[m] = *(const bf16x8*)(Ap + m * 16 * 32);
            #pragma unroll
            for (int n = 0; n < 4; n++) bfr[n] = *(const bf16x8*)(Bp + n * 16 * 32);
            #pragma unroll
            for (int m = 0; m < 4; m++)
                #pragma unroll
                for (int n = 0; n < 4; n++)
                    acc[m][n] = __builtin_amdgcn_mfma_f32_16x16x32_bf16(af[m], bfr[n], acc[m][n], 0, 0, 0);
            __syncthreads();
        }
        int col = l & 15, rg = l >> 4;
        #pragma unroll
        for (int m = 0; m < 4; m++)
            #pragma unroll
            for (int j = 0; j < 4; j++) {
                int gc = c0 + wr * 64 + m * 16 + rg * 4 + j;
                #pragma unroll
                for (int n = 0; n < 4; n++)
                    M[(size_t)gc * 1024 + n0 + wc * 64 + n * 16 + col] = __float2bfloat16(acc[m][n][j]);
            }
    }
}

// ------------------------------------------------------- attn[b][t][s] = softmax_s(theta.phi)
__global__ __launch_bounds__(64) void attn_kernel(const float* __restrict__ theta,
                                                  const float* __restrict__ phi,
                                                  float* __restrict__ attn) {
    __shared__ float th[4096], ph[4096];
    int b = blockIdx.x, lane = threadIdx.x;
    for (int i = lane; i < 4096; i += 64) {
        th[i] = theta[(size_t)b * 4096 + i];
        ph[i] = phi[(size_t)b * 4096 + i];
    }
    __syncthreads();
    int t = lane >> 3, s = lane & 7;
    float f = 0.0f;
    #pragma unroll 8
    for (int ic = 0; ic < 512; ic++) f += th[ic * 8 + t] * ph[ic * 8 + s];
    float m = f;
    m = fmaxf(m, __shfl_xor(m, 1));
    m = fmaxf(m, __shfl_xor(m, 2));
    m = fmaxf(m, __shfl_xor(m, 4));
    float e = __expf(f - m);
    float sum = e;
    sum += __shfl_xor(sum, 1); sum += __shfl_xor(sum, 2); sum += __shfl_xor(sum, 4);
    attn[b * 64 + lane] = e / sum;
}

// ===== mix v2: full-row coalesced reads. block = (b, 32-channel chunk), grid 1024 =====
// xmt[b][t*128+hw][c] = sum_s attn[b][t][s] * x[b][c][s][hw]
// Phase 1: stream x[b][c0:c0+32][*][*] (128 KB, 4KB/wave-instr) -> bf16 LDS [ci][s*128+hw]
// (per-ci stride 1028 -> 2-way banks = free). Phase 2: per (ci, hw-pair): 8 u32 LDS reads,
// 128 FMA, 16 bf16 stores in 64B c-contiguous runs.
__global__ __launch_bounds__(256) void mix_kernel(const float* __restrict__ x,
                                                  const float* __restrict__ attn,
                                                  __hip_bfloat16* __restrict__ xmt) {
    int orig = blockIdx.x;
    int wg = (orig & 7) * 128 + (orig >> 3);      // XCD chunk (1024 % 8 == 0)
    int b = wg >> 5;
    int c0 = (wg & 31) * 32;
    __shared__ float at[64];
    __shared__ __align__(8) unsigned short xls[32 * 1028];
    int tid = threadIdx.x;
    if (tid < 64) at[tid] = attn[b * 64 + tid];
    const float* xb = x + ((size_t)b << 20) + (size_t)c0 * 1024;
    #pragma unroll
    for (int k = 0; k < 32; ++k) {
        int f4 = tid + k * 256;                   // 0..8191
        float4 v = *(const float4*)(xb + (size_t)f4 * 4);
        int ci = f4 >> 8;
        int rem = (f4 & 255) * 4;
        unsigned short h[4];
        h[0] = f2bf(v.x); h[1] = f2bf(v.y); h[2] = f2bf(v.z); h[3] = f2bf(v.w);
        *(ushort4*)(&xls[ci * 1028 + rem]) = *(const ushort4*)h;
    }
    __syncthreads();
    int ci = tid & 31, h2 = tid >> 5;
    const unsigned short* basep = &xls[ci * 1028];
    __hip_bfloat16* ob = xmt + ((size_t)b << 20) + c0 + ci;
    #pragma unroll
    for (int i = 0; i < 8; ++i) {
        int hw0 = (h2 + 8 * i) * 2;
        float o0[8] = {}, o1[8] = {};
        #pragma unroll
        for (int s = 0; s < 8; ++s) {
            unsigned int pr = *(const unsigned int*)(basep + s * 128 + hw0);
            float v0 = __uint_as_float(pr << 16);
            float v1 = __uint_as_float(pr & 0xffff0000u);
            #pragma unroll
            for (int t = 0; t < 8; ++t) {
                float a = at[t * 8 + s];
                o0[t] = fmaf(a, v0, o0[t]);
                o1[t] = fmaf(a, v1, o1[t]);
            }
        }
        #pragma unroll
        for (int t = 0; t < 8; ++t) {
            size_t nn = (size_t)(t * 128 + hw0) * 1024;
            ob[nn] = __float2bfloat16(o0[t]);
            ob[nn + 1024] = __float2bfloat16(o1[t]);
        }
    }
}

// ===== 128x128-tile / 4-wave GEMM, K32 double-buffer + counted vmcnt, 3 blocks/CU (R9) =====
__global__ __launch_bounds__(256, 3) void gemm128_kernel(
        const __hip_bfloat16* __restrict__ Mw,    // [1024][1024]  (c, k)
        const __hip_bfloat16* __restrict__ xmt,   // [32][1024][1024] (n, k)
        const float* __restrict__ x,              // [32][1024][1024] (c, n)
        const float* __restrict__ inv, const float* __restrict__ shift,
        float* __restrict__ out) {
    __shared__ __align__(16) __hip_bfloat16 HBs[16384];        // 32 KiB = 2 x 16 KiB
    char* AH = (char*)HBs;
    const int BUFB = 16384;

    int orig = blockIdx.x;
    int bid = (orig & 7) * 256 + (orig >> 3);     // XCD chunk: 4 batches/XCD -> L2 locality
    int b = bid >> 6;
    int mb = (bid >> 3) & 7;
    int nb = bid & 7;
    int c0 = mb * 128, n0 = nb * 128;

    int tid = threadIdx.x;
    int w = tid >> 6, l = tid & 63;
    int wr = w >> 1, wc = w & 1;                  // 2x2 waves; wave out = 64(M) x 64(N)

    int sgl = (((l & 3) - ((l >> 3) & 3)) & 3);
    const __hip_bfloat16* aS = Mw + (size_t)(c0 + w * 16 + (l >> 2)) * 1024 + sgl * 8;
    const __hip_bfloat16* bS = xmt + ((size_t)b << 20) + (size_t)(n0 + w * 16 + (l >> 2)) * 1024 + sgl * 8;
    int stBase = w * 1024;

    int rdSlot = ((l >> 4) + (((l & 15) >> 1) & 3)) & 3;
    int aRdBase = (wr * 64 + (l & 15)) * 64 + rdSlot * 16;
    int bRdBase = 8192 + (wc * 64 + (l & 15)) * 64 + rdSlot * 16;

    f32x4 acc[4][4] = {};

    #define ISSUE(q) do {                                                       \
        gload_lds16(aS,             AH + (q) * BUFB + stBase);                  \
        gload_lds16(aS + 64 * 1024, AH + (q) * BUFB + 4096 + stBase);           \
        gload_lds16(bS,             AH + (q) * BUFB + 8192 + stBase);           \
        gload_lds16(bS + 64 * 1024, AH + (q) * BUFB + 12288 + stBase);          \
        aS += 32; bS += 32;                                                     \
    } while (0)

    #define V4 asm volatile("s_waitcnt vmcnt(4)" ::: "memory")
    #define V0 asm volatile("s_waitcnt vmcnt(0)" ::: "memory")
    #define SB0 __builtin_amdgcn_sched_barrier(0)
    #define BAR __builtin_amdgcn_s_barrier()
    #define LGKM0 asm volatile("s_waitcnt lgkmcnt(0)" ::: "memory")

    #define HSTEP(q, MODE) do {                                                 \
        const char* bp = AH + (q) * BUFB;                                       \
        bf16x8 af0 = *(const bf16x8*)(bp + aRdBase);                            \
        bf16x8 af1 = *(const bf16x8*)(bp + aRdBase + 1024);                     \
        bf16x8 af2 = *(const bf16x8*)(bp + aRdBase + 2048);                     \
        bf16x8 af3 = *(const bf16x8*)(bp + aRdBase + 3072);                     \
        bf16x8 bf0 = *(const bf16x8*)(bp + bRdBase);                            \
        bf16x8 bf1 = *(const bf16x8*)(bp + bRdBase + 1024);                     \
        bf16x8 bf2 = *(const bf16x8*)(bp + bRdBase + 2048);                     \
        bf16x8 bf3 = *(const bf16x8*)(bp + bRdBase + 3072);                     \
        LGKM0; SB0;                                                             \
        BAR;                                                                    \
        if ((MODE) == 0) ISSUE(q);                                              \
        SB0;                                                                    \
        __builtin_amdgcn_s_setprio(1);                                          \
        _Pragma("unroll")                                                       \
        for (int n = 0; n < 4; ++n) {                                           \
            bf16x8 bfn = (n == 0) ? bf0 : (n == 1) ? bf1 : (n == 2) ? bf2 : bf3;\
            acc[0][n] = __builtin_amdgcn_mfma_f32_16x16x32_bf16(af0, bfn, acc[0][n], 0, 0, 0); \
            acc[1][n] = __builtin_amdgcn_mfma_f32_16x16x32_bf16(af1, bfn, acc[1][n], 0, 0, 0); \
            acc[2][n] = __builtin_amdgcn_mfma_f32_16x16x32_bf16(af2, bfn, acc[2][n], 0, 0, 0); \
            acc[3][n] = __builtin_amdgcn_mfma_f32_16x16x32_bf16(af3, bfn, acc[3][n], 0, 0, 0); \
        }                                                                       \
        __builtin_amdgcn_s_setprio(0);                                          \
        SB0;                                                                    \
        if ((MODE) == 0) { V4; BAR; SB0; }                                      \
        else if ((MODE) == 1) { V0; BAR; SB0; }                                 \
    } while (0)

    ISSUE(0); ISSUE(1);
    V4; BAR; SB0;

    #pragma unroll 1
    for (int t = 0; t < 15; ++t) {
        HSTEP(0, 0);
        HSTEP(1, 0);
    }
    HSTEP(0, 1);
    HSTEP(1, 2);

    #undef ISSUE
    #undef HSTEP
    #undef V4
    #undef V0
    #undef SB0
    #undef BAR
    #undef LGKM0

    int col = l & 15, rg = l >> 4;
    const float* xb = x + ((size_t)b << 20);
    float* ob = out + ((size_t)b << 20);
    #pragma unroll
    for (int mi = 0; mi < 4; ++mi) {
        #pragma unroll
        for (int j = 0; j < 4; ++j) {
            int gc = c0 + wr * 64 + mi * 16 + rg * 4 + j;
            float iv = inv[gc], sh = shift[gc];
            size_t rowoff = (size_t)gc * 1024 + n0 + wc * 64 + col;
            #pragma unroll
            for (int n = 0; n < 4; ++n) {
                size_t idx = rowoff + n * 16;
                ob[idx] = acc[mi][n][j] * iv + sh + xb[idx];
            }
        }
    }
}

extern "C" void kernel_launch(void* const* d_in, const int* in_sizes, int n_in,
                              void* d_out, int out_size, void* d_ws, size_t ws_size,
                              hipStream_t stream) {
    const float* x    = (const float*)d_in[0];
    const float* g_w  = (const float*)d_in[1];
    const float* g_b  = (const float*)d_in[2];
    const float* th_w = (const float*)d_in[3];
    const float* th_b = (const float*)d_in[4];
    const float* ph_w = (const float*)d_in[5];
    const float* ph_b = (const float*)d_in[6];
    const float* w_w  = (const float*)d_in[7];
    const float* w_b  = (const float*)d_in[8];
    const float* gam  = (const float*)d_in[9];
    const float* bet  = (const float*)d_in[10];
    const float* mea  = (const float*)d_in[11];
    const float* var  = (const float*)d_in[12];
    float* out = (float*)d_out;
    char* ws = (char*)d_ws;

    __hip_bfloat16* xmt = (__hip_bfloat16*)ws;                    // 64 MiB (written by mix, late)
    __hip_bfloat16* Mw  = (__hip_bfloat16*)(ws + 67108864);       // 2 MiB
    float* xbar  = (float*)(ws + 69206016);                       // 1 MiB
    float* theta = (float*)(ws + 70254592);                       // 512 KiB
    float* phi   = (float*)(ws + 70778880);                       // 512 KiB
    float* attn  = (float*)(ws + 71303168);                       // 8 KiB
    float* inv   = (float*)(ws + 71311360);                       // 4 KiB
    float* shift = (float*)(ws + 71315456);                       // 4 KiB
    // gwt/wwb overlay the xmt region: consumed by stage2 (prepM) BEFORE mix writes xmt
    __hip_bfloat16* gwt = (__hip_bfloat16*)ws;                    // 1 MiB
    __hip_bfloat16* wwb = (__hip_bfloat16*)(ws + 1048576);        // 1 MiB

    hipLaunchKernelGGL(early_kernel, dim3(17184), dim3(256), 0, stream,
                       x, xbar, g_w, w_w, gwt, wwb,
                       g_b, w_b, gam, bet, mea, var, inv, shift);
    hipLaunchKernelGGL(stage2_kernel, dim3(1088), dim3(256), 0, stream,
                       xbar, th_w, th_b, ph_w, ph_b, theta, phi, wwb, gwt, Mw);
    hipLaunchKernelGGL(attn_kernel, dim3(32), dim3(64), 0, stream, theta, phi, attn);
    hipLaunchKernelGGL(mix_kernel, dim3(1024), dim3(256), 0, stream, x, attn, xmt);
    hipLaunchKernelGGL(gemm128_kernel, dim3(2048), dim3(256), 0, stream,
                       Mw, xmt, x, inv, shift, out);
}